// Round 4
// baseline (743.409 us; speedup 1.0000x reference)
//
#include <hip/hip_runtime.h>

typedef __attribute__((ext_vector_type(8))) short short8;
typedef __attribute__((ext_vector_type(4))) float float4v;

#define NNODES 8192
#define SEQLEN 256

static __device__ __forceinline__ float bf2f(unsigned short u) {
  union { unsigned u; float f; } v; v.u = ((unsigned)u) << 16; return v.f;
}
static __device__ __forceinline__ unsigned short f2bf(float f) {
  union { float f; unsigned u; } v; v.f = f;
  unsigned r = v.u + 0x7FFFu + ((v.u >> 16) & 1u);
  return (unsigned short)(r >> 16);
}
static __device__ __forceinline__ float sigm(float x) {
  float e = __builtin_amdgcn_exp2f(-1.44269504089f * x);
  return __builtin_amdgcn_rcpf(1.f + e);
}
static __device__ __forceinline__ float tanh_(float x) {
  float e = __builtin_amdgcn_exp2f(2.88539008178f * fminf(x, 20.f));
  return (e - 1.f) * __builtin_amdgcn_rcpf(e + 1.f);
}
static __device__ __forceinline__ void split8(const float* v, short8& hi, short8& lo) {
#pragma unroll
  for (int j = 0; j < 8; ++j) {
    unsigned short h = f2bf(v[j]);
    hi[j] = (short)h;
    lo[j] = (short)f2bf(v[j] - bf2f(h));
  }
}
// distributed 4x4 transpose: value (reg r, lanehi H=c>>2) -> (reg H, lanehi r)
static __device__ __forceinline__ float4v tr4(float4v v, int lane) {
  float t0 = __shfl_xor(v[0], 8, 64), t1 = __shfl_xor(v[1], 8, 64);
  float t2 = __shfl_xor(v[2], 8, 64), t3 = __shfl_xor(v[3], 8, 64);
  bool h1 = (lane & 8) != 0;
  float4v a;
  a[0] = h1 ? t2 : v[0]; a[1] = h1 ? t3 : v[1];
  a[2] = h1 ? v[2] : t0; a[3] = h1 ? v[3] : t1;
  t0 = __shfl_xor(a[0], 4, 64); t1 = __shfl_xor(a[1], 4, 64);
  t2 = __shfl_xor(a[2], 4, 64); t3 = __shfl_xor(a[3], 4, 64);
  bool h0 = (lane & 4) != 0;
  float4v b;
  b[0] = h0 ? t1 : a[0]; b[1] = h0 ? a[1] : t0;
  b[2] = h0 ? t3 : a[2]; b[3] = h0 ? a[3] : t2;
  return b;
}

// 8 waves per 16-node group. Wave w's B-tile col n -> gate row (n>>2)*32 + w*4 + (n&3),
// so wave w's D holds all 4 gates for hidden w*4..w*4+3 -> in-wave 4x4 transpose,
// no z-exchange through LDS. 2 barriers/step (h1, h2 planes, double-buffered).
__global__ __launch_bounds__(512, 4)
void lstm_fused(const float* __restrict__ x,
                const float* __restrict__ Wih1, const float* __restrict__ Whh1,
                const float* __restrict__ bih1, const float* __restrict__ bhh1,
                const float* __restrict__ ln_g, const float* __restrict__ ln_b,
                const float* __restrict__ Wih2, const float* __restrict__ Whh2,
                const float* __restrict__ bih2, const float* __restrict__ bhh2,
                float* __restrict__ h2out)
{
  const int tid = threadIdx.x;
  const int w = tid >> 6;
  const int lane = tid & 63;
  const int c = lane & 15;
  const int q = lane >> 4;
  const int g4 = c >> 2, j4 = c & 3;
  const int nd = q * 4 + g4;        // post-transpose: my node (local)
  const int hid = w * 4 + j4;       // my hidden unit
  const int nodeBase = blockIdx.x * 16;

  __shared__ float xlds[16 * 257];
  __shared__ __align__(16) unsigned short h1hi[16 * 40], h1lo[16 * 40];
  __shared__ __align__(16) unsigned short h2hi[16 * 40], h2lo[16 * 40];

  for (int i = tid; i < 16 * 256; i += 512) {
    int nn = i >> 8, tt = i & 255;
    xlds[nn * 257 + tt] = x[(size_t)(nodeBase + nn) * SEQLEN + tt];
  }

  // B fragments: col n=c -> global gate row brow
  short8 Bh1h, Bh1l, Bi2h, Bi2l, Bh2h, Bh2l;
  {
    int brow = g4 * 32 + w * 4 + j4;
    float v[8];
#pragma unroll
    for (int j = 0; j < 8; ++j) v[j] = Whh1[brow * 32 + q * 8 + j];
    split8(v, Bh1h, Bh1l);
#pragma unroll
    for (int j = 0; j < 8; ++j) v[j] = Wih2[brow * 32 + q * 8 + j] * ln_g[q * 8 + j];
    split8(v, Bi2h, Bi2l);
#pragma unroll
    for (int j = 0; j < 8; ++j) v[j] = Whh2[brow * 32 + q * 8 + j];
    split8(v, Bh2h, Bh2l);
  }
  // cell constants, reg g = gate g, my hid: row = g*32 + hid
  float w1v[4], b1v[4], Gv[4], b2v[4];
#pragma unroll
  for (int g = 0; g < 4; ++g) {
    int row = g * 32 + hid;
    w1v[g] = Wih1[row];
    b1v[g] = bih1[row] + bhh1[row];
    float sG = 0.f, sB = 0.f;
    for (int k = 0; k < 32; ++k) {
      float wv = Wih2[row * 32 + k];
      sG += wv * ln_g[k];
      sB += wv * ln_b[k];
    }
    Gv[g] = sG;
    b2v[g] = sB + bih2[row] + bhh2[row];
  }
  const float Gpre = Gv[g4];   // pre-transpose lane = column (gate g4, hid w*4+j4)

  short8 h1h = {0,0,0,0,0,0,0,0}, h1l = {0,0,0,0,0,0,0,0};
  short8 h2h = {0,0,0,0,0,0,0,0}, h2l = {0,0,0,0,0,0,0,0};
  float c1 = 0.f, c2 = 0.f;
  const float4v z4 = {0.f, 0.f, 0.f, 0.f};
  __syncthreads();

  for (int t = 0; t < SEQLEN; ++t) {
    // ---- layer1 matmul: D[m=node][n=(gate,hid)] ----
    float4v za = __builtin_amdgcn_mfma_f32_16x16x32_bf16(h1l, Bh1h, z4, 0, 0, 0);
    za = __builtin_amdgcn_mfma_f32_16x16x32_bf16(h1h, Bh1l, za, 0, 0, 0);
    za = __builtin_amdgcn_mfma_f32_16x16x32_bf16(h1h, Bh1h, za, 0, 0, 0);
    za = tr4(za, lane);               // reg = gate, lane owns (nd, hid)

    // ---- cell layer1 ----
    {
      float xv = xlds[nd * 257 + t];
      float zi = za[0] + xv * w1v[0] + b1v[0];
      float zf = za[1] + xv * w1v[1] + b1v[1];
      float zg = za[2] + xv * w1v[2] + b1v[2];
      float zo = za[3] + xv * w1v[3] + b1v[3];
      c1 = sigm(zf) * c1 + sigm(zi) * tanh_(zg);
      float hv = sigm(zo) * tanh_(c1);
      unsigned short hi = f2bf(hv);
      h1hi[nd * 40 + hid] = hi;
      h1lo[nd * 40 + hid] = f2bf(hv - bf2f(hi));
    }
    __syncthreads();                  // B1
    h1h = *(const short8*)&h1hi[c * 40 + q * 8];
    h1l = *(const short8*)&h1lo[c * 40 + q * 8];

    // ---- LN stats for node c (all waves, redundant) ----
    float s = 0.f, s2 = 0.f;
#pragma unroll
    for (int j = 0; j < 8; ++j) {
      float hv = bf2f((unsigned short)h1h[j]) + bf2f((unsigned short)h1l[j]);
      s += hv; s2 += hv * hv;
    }
    s  += __shfl_xor(s, 16, 64);  s  += __shfl_xor(s, 32, 64);
    s2 += __shfl_xor(s2, 16, 64); s2 += __shfl_xor(s2, 32, 64);
    float mu = s * (1.f / 32.f);
    float var = s2 * (1.f / 32.f) - mu * mu;
    float rstd = rsqrtf(var + 1e-5f);
    float bmu = rstd * mu;
    // redistribute per-register (pre-transpose reg r = node q*4+r)
    float ar[4], br[4];
#pragma unroll
    for (int r = 0; r < 4; ++r) {
      ar[r] = __shfl(rstd, q * 4 + r, 64);
      br[r] = __shfl(bmu,  q * 4 + r, 64);
    }

    // ---- layer2 matmuls ----
    float4v da = __builtin_amdgcn_mfma_f32_16x16x32_bf16(h1l, Bi2h, z4, 0, 0, 0);
    da = __builtin_amdgcn_mfma_f32_16x16x32_bf16(h1h, Bi2l, da, 0, 0, 0);
    da = __builtin_amdgcn_mfma_f32_16x16x32_bf16(h1h, Bi2h, da, 0, 0, 0);
    float4v db = __builtin_amdgcn_mfma_f32_16x16x32_bf16(h2l, Bh2h, z4, 0, 0, 0);
    db = __builtin_amdgcn_mfma_f32_16x16x32_bf16(h2h, Bh2l, db, 0, 0, 0);
    db = __builtin_amdgcn_mfma_f32_16x16x32_bf16(h2h, Bh2h, db, 0, 0, 0);
    float4v pre;
#pragma unroll
    for (int r = 0; r < 4; ++r)
      pre[r] = ar[r] * da[r] + db[r] - br[r] * Gpre;
    pre = tr4(pre, lane);

    // ---- cell layer2 ----
    {
      float zi = pre[0] + b2v[0];
      float zf = pre[1] + b2v[1];
      float zg = pre[2] + b2v[2];
      float zo = pre[3] + b2v[3];
      c2 = sigm(zf) * c2 + sigm(zi) * tanh_(zg);
      float hv = sigm(zo) * tanh_(c2);
      unsigned short hi = f2bf(hv);
      h2hi[nd * 40 + hid] = hi;
      h2lo[nd * 40 + hid] = f2bf(hv - bf2f(hi));
      if (t == SEQLEN - 1)
        h2out[(size_t)(nodeBase + nd) * 32 + hid] = hv;
    }
    __syncthreads();                  // B2
    h2h = *(const short8*)&h2hi[c * 40 + q * 8];
    h2l = *(const short8*)&h2lo[c * 40 + q * 8];
  }
}

// ---------------- GCN (all f32) ----------------
__global__ void deg_init(float* __restrict__ deg) {
  int i = blockIdx.x * 256 + threadIdx.x;
  if (i < NNODES) deg[i] = 1.f;
}
__global__ void deg_acc(const int* __restrict__ ei, const float* __restrict__ ew,
                        float* __restrict__ deg, int E) {
  int e = blockIdx.x * 256 + threadIdx.x;
  if (e < E) atomicAdd(&deg[ei[E + e]], ew[e]);
}
__global__ void gcn_mm1(const float* __restrict__ h2, const float* __restrict__ Wg1,
                        const float* __restrict__ deg, float* __restrict__ dinv,
                        float* __restrict__ hW, float* __restrict__ agg) {
  __shared__ float wg[32 * 33];
  int tid = threadIdx.x;
  for (int i = tid; i < 1024; i += 256) wg[(i >> 5) * 33 + (i & 31)] = Wg1[i];
  __syncthreads();
  int nl = tid >> 5, j = tid & 31;
  int node = blockIdx.x * 8 + nl;
  const float* hr = h2 + (size_t)node * 32;
  float acc = 0.f;
#pragma unroll
  for (int k = 0; k < 32; ++k) acc = fmaf(hr[k], wg[k * 33 + j], acc);
  float dv = rsqrtf(deg[node]);
  if (j == 0) dinv[node] = dv;
  hW[(size_t)node * 32 + j] = acc;
  agg[(size_t)node * 32 + j] = acc * dv * dv;
}
__global__ void gcn_edge(const int* __restrict__ ei, const float* __restrict__ ew,
                         const float* __restrict__ dinv, const float* __restrict__ hW,
                         float* __restrict__ agg, int E) {
  int gid = blockIdx.x * 256 + threadIdx.x;
  int e = gid >> 5, j = gid & 31;
  if (e >= E) return;
  int s = ei[e], d = ei[E + e];
  float coeff = dinv[s] * ew[e] * dinv[d];
  atomicAdd(&agg[(size_t)d * 32 + j], coeff * hW[(size_t)s * 32 + j]);
}
__global__ void gcn_mid(const float* __restrict__ bg1, const float* __restrict__ Wg2,
                        const float* __restrict__ dinv,
                        float* __restrict__ hW, float* __restrict__ agg) {
  __shared__ float wg[32 * 33];
  __shared__ float g1buf[8][33];
  int tid = threadIdx.x;
  for (int i = tid; i < 1024; i += 256) wg[(i >> 5) * 33 + (i & 31)] = Wg2[i];
  int nl = tid >> 5, j = tid & 31;
  int node = blockIdx.x * 8 + nl;
  float v = agg[(size_t)node * 32 + j] + bg1[j];
  g1buf[nl][j] = (v > 0.f) ? v : expm1f(v);
  __syncthreads();
  float acc = 0.f;
#pragma unroll
  for (int k = 0; k < 32; ++k) acc = fmaf(g1buf[nl][k], wg[k * 33 + j], acc);
  float dv = dinv[node];
  hW[(size_t)node * 32 + j] = acc;
  agg[(size_t)node * 32 + j] = acc * dv * dv;
}
__global__ void final_k(const float* __restrict__ h2, const float* __restrict__ agg,
                        const float* __restrict__ bg2, const float* __restrict__ Wfc,
                        const float* __restrict__ bfc, float* __restrict__ out) {
  int node = blockIdx.x * 256 + threadIdx.x;
  if (node >= NNODES) return;
  const float* ar = agg + (size_t)node * 32;
  float msum = 0.f;
#pragma unroll
  for (int k = 0; k < 32; ++k) {
    float v = ar[k] + bg2[k];
    msum += (v > 0.f) ? v : expm1f(v);
  }
  float mean = msum * (1.f / 32.f);
  const float* hr = h2 + (size_t)node * 32;
  float o0 = bfc[0], o1 = bfc[1];
#pragma unroll
  for (int k = 0; k < 32; ++k) {
    float hv = hr[k];
    o0 = fmaf(hv, Wfc[k], o0);
    o1 = fmaf(hv, Wfc[33 + k], o1);
  }
  o0 = fmaf(mean, Wfc[32], o0);
  o1 = fmaf(mean, Wfc[65], o1);
  float m = fmaxf(o0, o1);
  float l = m + logf(expf(o0 - m) + expf(o1 - m));
  out[node * 2 + 0] = o0 - l;
  out[node * 2 + 1] = o1 - l;
}

extern "C" void kernel_launch(void* const* d_in, const int* in_sizes, int n_in,
                              void* d_out, int out_size, void* d_ws, size_t ws_size,
                              hipStream_t stream) {
  const float* x    = (const float*)d_in[0];
  const float* ew   = (const float*)d_in[1];
  const float* Wih1 = (const float*)d_in[2];
  const float* Whh1 = (const float*)d_in[3];
  const float* bih1 = (const float*)d_in[4];
  const float* bhh1 = (const float*)d_in[5];
  const float* ln_g = (const float*)d_in[6];
  const float* ln_b = (const float*)d_in[7];
  const float* Wih2 = (const float*)d_in[8];
  const float* Whh2 = (const float*)d_in[9];
  const float* bih2 = (const float*)d_in[10];
  const float* bhh2 = (const float*)d_in[11];
  const float* Wg1  = (const float*)d_in[12];
  const float* bg1  = (const float*)d_in[13];
  const float* Wg2  = (const float*)d_in[14];
  const float* bg2  = (const float*)d_in[15];
  const float* Wfc  = (const float*)d_in[16];
  const float* bfc  = (const float*)d_in[17];
  const int* ei     = (const int*)d_in[18];
  float* out = (float*)d_out;
  const int E = in_sizes[1];

  float* ws   = (float*)d_ws;
  float* h2   = ws;
  float* hW   = ws + 262144;
  float* agg  = ws + 524288;
  float* deg  = ws + 786432;
  float* dinv = ws + 794624;

  hipLaunchKernelGGL(deg_init, dim3(32), dim3(256), 0, stream, deg);
  hipLaunchKernelGGL(deg_acc, dim3((E + 255) / 256), dim3(256), 0, stream, ei, ew, deg, E);
  hipLaunchKernelGGL(lstm_fused, dim3(NNODES / 16), dim3(512), 0, stream,
                     x, Wih1, Whh1, bih1, bhh1, ln_g, ln_b,
                     Wih2, Whh2, bih2, bhh2, h2);
  hipLaunchKernelGGL(gcn_mm1, dim3(NNODES / 8), dim3(256), 0, stream, h2, Wg1, deg, dinv, hW, agg);
  hipLaunchKernelGGL(gcn_edge, dim3((E * 32 + 255) / 256), dim3(256), 0, stream, ei, ew, dinv, hW, agg, E);
  hipLaunchKernelGGL(gcn_mid, dim3(NNODES / 8), dim3(256), 0, stream, bg1, Wg2, dinv, hW, agg);
  hipLaunchKernelGGL(gcn_edge, dim3((E * 32 + 255) / 256), dim3(256), 0, stream, ei, ew, dinv, hW, agg, E);
  hipLaunchKernelGGL(final_k, dim3(NNODES / 256), dim3(256), 0, stream, h2, agg, bg2, Wfc, bfc, out);
}

// Round 5
// 583.456 us; speedup vs baseline: 1.2741x; 1.2741x over previous
//
#include <hip/hip_runtime.h>

typedef __attribute__((ext_vector_type(8))) short short8;
typedef __attribute__((ext_vector_type(4))) float float4v;

#define NNODES 8192
#define SEQLEN 256

static __device__ __forceinline__ float bf2f(unsigned short u) {
  union { unsigned u; float f; } v; v.u = ((unsigned)u) << 16; return v.f;
}
static __device__ __forceinline__ unsigned short f2bf(float f) {
  union { float f; unsigned u; } v; v.f = f;
  unsigned r = v.u + 0x7FFFu + ((v.u >> 16) & 1u);
  return (unsigned short)(r >> 16);
}
static __device__ __forceinline__ float sigm(float x) {
  float e = __builtin_amdgcn_exp2f(-1.44269504089f * x);
  return __builtin_amdgcn_rcpf(1.f + e);
}
static __device__ __forceinline__ float tanh_(float x) {
  float e = __builtin_amdgcn_exp2f(2.88539008178f * fminf(x, 20.f));
  return (e - 1.f) * __builtin_amdgcn_rcpf(e + 1.f);
}
static __device__ __forceinline__ void split8(const float* v, short8& hi, short8& lo) {
#pragma unroll
  for (int j = 0; j < 8; ++j) {
    unsigned short h = f2bf(v[j]);
    hi[j] = (short)h;
    lo[j] = (short)f2bf(v[j] - bf2f(h));
  }
}
static __device__ __forceinline__ float bperm(int byteaddr, float v) {
  return __int_as_float(__builtin_amdgcn_ds_bpermute(byteaddr, __float_as_int(v)));
}

// v5: 8 waves / 16-node group. B cols permuted: col n -> gate row (n&3)*32 + w*4 + (n>>2),
// so z lives wave-private in [node][hid][gate] LDS layout (no barrier for z exchange;
// consumer gets all 4 gates with one ds_read_b128). h planes bf16 single (B keeps hi+lo
// split). LN folded producer-side via 8 fixed-address ds_bpermute. 2 barriers/step.
__global__ __launch_bounds__(512, 4)
void lstm_fused(const float* __restrict__ x,
                const float* __restrict__ Wih1, const float* __restrict__ Whh1,
                const float* __restrict__ bih1, const float* __restrict__ bhh1,
                const float* __restrict__ ln_g, const float* __restrict__ ln_b,
                const float* __restrict__ Wih2, const float* __restrict__ Whh2,
                const float* __restrict__ bih2, const float* __restrict__ bhh2,
                float* __restrict__ h2out)
{
  const int tid = threadIdx.x;
  const int w = tid >> 6;
  const int lane = tid & 63;
  const int c = lane & 15;          // MFMA col / A-row
  const int q = lane >> 4;          // quad
  const int cn = lane >> 2;         // cell node 0..15
  const int ch = lane & 3;          // cell hid low bits
  const int hid = w * 4 + ch;       // cell hidden unit
  const int nodeBase = blockIdx.x * 16;

  __shared__ float xlds[16 * 257];
  __shared__ __align__(16) float zbuf[16 * 132];
  __shared__ __align__(16) unsigned short h1p[16 * 40];
  __shared__ __align__(16) unsigned short h2p[16 * 40];

  for (int i = tid; i < 16 * 256; i += 512) {
    int nn = i >> 8, tt = i & 255;
    xlds[nn * 257 + tt] = x[(size_t)(nodeBase + nn) * SEQLEN + tt];
  }

  // ---- B fragments (col c -> brow), hi+lo split ----
  const int brow = (c & 3) * 32 + w * 4 + (c >> 2);
  short8 Bh1h, Bh1l, Bi2h, Bi2l, Bh2h, Bh2l;
  float Gpre;
  {
    float v[8];
#pragma unroll
    for (int j = 0; j < 8; ++j) v[j] = Whh1[brow * 32 + q * 8 + j];
    split8(v, Bh1h, Bh1l);
#pragma unroll
    for (int j = 0; j < 8; ++j) v[j] = Wih2[brow * 32 + q * 8 + j] * ln_g[q * 8 + j];
    split8(v, Bi2h, Bi2l);
#pragma unroll
    for (int j = 0; j < 8; ++j) v[j] = Whh2[brow * 32 + q * 8 + j];
    split8(v, Bh2h, Bh2l);
    float sG = 0.f;
    for (int k = 0; k < 32; ++k) sG += Wih2[brow * 32 + k] * ln_g[k];
    Gpre = sG;
  }
  // ---- cell constants: gate g row = g*32 + hid ----
  float w1v[4], b1v[4], b2v[4];
#pragma unroll
  for (int g = 0; g < 4; ++g) {
    int row = g * 32 + hid;
    w1v[g] = Wih1[row];
    b1v[g] = bih1[row] + bhh1[row];
    float sB = 0.f;
    for (int k = 0; k < 32; ++k) sB += Wih2[row * 32 + k] * ln_b[k];
    b2v[g] = sB + bih2[row] + bhh2[row];
  }

  // ---- loop-invariant LDS addresses ----
  int zW[4];
#pragma unroll
  for (int r = 0; r < 4; ++r) zW[r] = (q * 4 + r) * 132 + w * 16 + c;
  const int zR = cn * 132 + hid * 4;
  const int hWr = cn * 40 + hid;
  const int hRd = c * 40 + q * 8;
  int bp[4];
#pragma unroll
  for (int r = 0; r < 4; ++r) bp[r] = (q * 4 + r) * 4;   // bpermute byte addr

  short8 h1A = {0,0,0,0,0,0,0,0};
  short8 h2A = {0,0,0,0,0,0,0,0};
  float c1 = 0.f, c2 = 0.f, hv2 = 0.f;
  const float4v z4 = {0.f, 0.f, 0.f, 0.f};
  __syncthreads();

  for (int t = 0; t < SEQLEN; ++t) {
    // ---- layer1: z1 = h1 @ Whh1^T (2 MFMAs: B hi+lo) ----
    float4v za = __builtin_amdgcn_mfma_f32_16x16x32_bf16(h1A, Bh1l, z4, 0, 0, 0);
    za = __builtin_amdgcn_mfma_f32_16x16x32_bf16(h1A, Bh1h, za, 0, 0, 0);
#pragma unroll
    for (int r = 0; r < 4; ++r) zbuf[zW[r]] = za[r];
    float4v z1v = *(const float4v*)&zbuf[zR];   // intra-wave, lgkm-ordered

    // ---- cell layer1 ----
    {
      float xv = xlds[cn * 257 + t];
      float zi = z1v[0] + xv * w1v[0] + b1v[0];
      float zf = z1v[1] + xv * w1v[1] + b1v[1];
      float zg = z1v[2] + xv * w1v[2] + b1v[2];
      float zo = z1v[3] + xv * w1v[3] + b1v[3];
      c1 = sigm(zf) * c1 + sigm(zi) * tanh_(zg);
      float hv = sigm(zo) * tanh_(c1);
      h1p[hWr] = f2bf(hv);
    }
    __syncthreads();                            // B1
    h1A = *(const short8*)&h1p[hRd];

    // ---- LN stats (redundant per wave; lane has node c) ----
    float s = 0.f, s2 = 0.f;
#pragma unroll
    for (int j = 0; j < 8; ++j) {
      float hf = bf2f((unsigned short)h1A[j]);
      s += hf; s2 = fmaf(hf, hf, s2);
    }
    s  += __shfl_xor(s, 16, 64);  s  += __shfl_xor(s, 32, 64);
    s2 += __shfl_xor(s2, 16, 64); s2 += __shfl_xor(s2, 32, 64);
    float mu = s * (1.f / 32.f);
    float var = s2 * (1.f / 32.f) - mu * mu;
    float rstd = rsqrtf(var + 1e-5f);
    float bmu = rstd * mu;

    // ---- layer2 matmuls (4 MFMAs) ----
    float4v da = __builtin_amdgcn_mfma_f32_16x16x32_bf16(h1A, Bi2l, z4, 0, 0, 0);
    da = __builtin_amdgcn_mfma_f32_16x16x32_bf16(h1A, Bi2h, da, 0, 0, 0);
    float4v db = __builtin_amdgcn_mfma_f32_16x16x32_bf16(h2A, Bh2l, z4, 0, 0, 0);
    db = __builtin_amdgcn_mfma_f32_16x16x32_bf16(h2A, Bh2h, db, 0, 0, 0);

    // per-D-row LN factors via fixed-address bpermute (row = q*4+r lives in lane q*4+r)
#pragma unroll
    for (int r = 0; r < 4; ++r) {
      float ar = bperm(bp[r], rstd);
      float br = bperm(bp[r], bmu);
      zbuf[zW[r]] = fmaf(ar, da[r], fmaf(-br, Gpre, db[r]));
    }
    float4v z2v = *(const float4v*)&zbuf[zR];

    // ---- cell layer2 ----
    {
      float zi = z2v[0] + b2v[0];
      float zf = z2v[1] + b2v[1];
      float zg = z2v[2] + b2v[2];
      float zo = z2v[3] + b2v[3];
      c2 = sigm(zf) * c2 + sigm(zi) * tanh_(zg);
      hv2 = sigm(zo) * tanh_(c2);
      h2p[hWr] = f2bf(hv2);
    }
    __syncthreads();                            // B2
    h2A = *(const short8*)&h2p[hRd];
  }
  h2out[(size_t)(nodeBase + cn) * 32 + hid] = hv2;
}

// ---------------- GCN (all f32) ----------------
__global__ void deg_init(float* __restrict__ deg) {
  int i = blockIdx.x * 256 + threadIdx.x;
  if (i < NNODES) deg[i] = 1.f;
}
__global__ void deg_acc(const int* __restrict__ ei, const float* __restrict__ ew,
                        float* __restrict__ deg, int E) {
  int e = blockIdx.x * 256 + threadIdx.x;
  if (e < E) atomicAdd(&deg[ei[E + e]], ew[e]);
}
__global__ void gcn_mm1(const float* __restrict__ h2, const float* __restrict__ Wg1,
                        const float* __restrict__ deg, float* __restrict__ dinv,
                        float* __restrict__ hW, float* __restrict__ agg) {
  __shared__ float wg[32 * 33];
  int tid = threadIdx.x;
  for (int i = tid; i < 1024; i += 256) wg[(i >> 5) * 33 + (i & 31)] = Wg1[i];
  __syncthreads();
  int nl = tid >> 5, j = tid & 31;
  int node = blockIdx.x * 8 + nl;
  const float* hr = h2 + (size_t)node * 32;
  float acc = 0.f;
#pragma unroll
  for (int k = 0; k < 32; ++k) acc = fmaf(hr[k], wg[k * 33 + j], acc);
  float dv = rsqrtf(deg[node]);
  if (j == 0) dinv[node] = dv;
  hW[(size_t)node * 32 + j] = acc;
  agg[(size_t)node * 32 + j] = acc * dv * dv;
}
__global__ void gcn_edge(const int* __restrict__ ei, const float* __restrict__ ew,
                         const float* __restrict__ dinv, const float* __restrict__ hW,
                         float* __restrict__ agg, int E) {
  int gid = blockIdx.x * 256 + threadIdx.x;
  int e = gid >> 5, j = gid & 31;
  if (e >= E) return;
  int s = ei[e], d = ei[E + e];
  float coeff = dinv[s] * ew[e] * dinv[d];
  atomicAdd(&agg[(size_t)d * 32 + j], coeff * hW[(size_t)s * 32 + j]);
}
__global__ void gcn_mid(const float* __restrict__ bg1, const float* __restrict__ Wg2,
                        const float* __restrict__ dinv,
                        float* __restrict__ hW, float* __restrict__ agg) {
  __shared__ float wg[32 * 33];
  __shared__ float g1buf[8][33];
  int tid = threadIdx.x;
  for (int i = tid; i < 1024; i += 256) wg[(i >> 5) * 33 + (i & 31)] = Wg2[i];
  int nl = tid >> 5, j = tid & 31;
  int node = blockIdx.x * 8 + nl;
  float v = agg[(size_t)node * 32 + j] + bg1[j];
  g1buf[nl][j] = (v > 0.f) ? v : expm1f(v);
  __syncthreads();
  float acc = 0.f;
#pragma unroll
  for (int k = 0; k < 32; ++k) acc = fmaf(g1buf[nl][k], wg[k * 33 + j], acc);
  float dv = dinv[node];
  hW[(size_t)node * 32 + j] = acc;
  agg[(size_t)node * 32 + j] = acc * dv * dv;
}
__global__ void final_k(const float* __restrict__ h2, const float* __restrict__ agg,
                        const float* __restrict__ bg2, const float* __restrict__ Wfc,
                        const float* __restrict__ bfc, float* __restrict__ out) {
  int node = blockIdx.x * 256 + threadIdx.x;
  if (node >= NNODES) return;
  const float* ar = agg + (size_t)node * 32;
  float msum = 0.f;
#pragma unroll
  for (int k = 0; k < 32; ++k) {
    float v = ar[k] + bg2[k];
    msum += (v > 0.f) ? v : expm1f(v);
  }
  float mean = msum * (1.f / 32.f);
  const float* hr = h2 + (size_t)node * 32;
  float o0 = bfc[0], o1 = bfc[1];
#pragma unroll
  for (int k = 0; k < 32; ++k) {
    float hv = hr[k];
    o0 = fmaf(hv, Wfc[k], o0);
    o1 = fmaf(hv, Wfc[33 + k], o1);
  }
  o0 = fmaf(mean, Wfc[32], o0);
  o1 = fmaf(mean, Wfc[65], o1);
  float m = fmaxf(o0, o1);
  float l = m + logf(expf(o0 - m) + expf(o1 - m));
  out[node * 2 + 0] = o0 - l;
  out[node * 2 + 1] = o1 - l;
}

extern "C" void kernel_launch(void* const* d_in, const int* in_sizes, int n_in,
                              void* d_out, int out_size, void* d_ws, size_t ws_size,
                              hipStream_t stream) {
  const float* x    = (const float*)d_in[0];
  const float* ew   = (const float*)d_in[1];
  const float* Wih1 = (const float*)d_in[2];
  const float* Whh1 = (const float*)d_in[3];
  const float* bih1 = (const float*)d_in[4];
  const float* bhh1 = (const float*)d_in[5];
  const float* ln_g = (const float*)d_in[6];
  const float* ln_b = (const float*)d_in[7];
  const float* Wih2 = (const float*)d_in[8];
  const float* Whh2 = (const float*)d_in[9];
  const float* bih2 = (const float*)d_in[10];
  const float* bhh2 = (const float*)d_in[11];
  const float* Wg1  = (const float*)d_in[12];
  const float* bg1  = (const float*)d_in[13];
  const float* Wg2  = (const float*)d_in[14];
  const float* bg2  = (const float*)d_in[15];
  const float* Wfc  = (const float*)d_in[16];
  const float* bfc  = (const float*)d_in[17];
  const int* ei     = (const int*)d_in[18];
  float* out = (float*)d_out;
  const int E = in_sizes[1];

  float* ws   = (float*)d_ws;
  float* h2   = ws;
  float* hW   = ws + 262144;
  float* agg  = ws + 524288;
  float* deg  = ws + 786432;
  float* dinv = ws + 794624;

  hipLaunchKernelGGL(deg_init, dim3(32), dim3(256), 0, stream, deg);
  hipLaunchKernelGGL(deg_acc, dim3((E + 255) / 256), dim3(256), 0, stream, ei, ew, deg, E);
  hipLaunchKernelGGL(lstm_fused, dim3(NNODES / 16), dim3(512), 0, stream,
                     x, Wih1, Whh1, bih1, bhh1, ln_g, ln_b,
                     Wih2, Whh2, bih2, bhh2, h2);
  hipLaunchKernelGGL(gcn_mm1, dim3(NNODES / 8), dim3(256), 0, stream, h2, Wg1, deg, dinv, hW, agg);
  hipLaunchKernelGGL(gcn_edge, dim3((E * 32 + 255) / 256), dim3(256), 0, stream, ei, ew, dinv, hW, agg, E);
  hipLaunchKernelGGL(gcn_mid, dim3(NNODES / 8), dim3(256), 0, stream, bg1, Wg2, dinv, hW, agg);
  hipLaunchKernelGGL(gcn_edge, dim3((E * 32 + 255) / 256), dim3(256), 0, stream, ei, ew, dinv, hW, agg, E);
  hipLaunchKernelGGL(final_k, dim3(NNODES / 256), dim3(256), 0, stream, h2, agg, bg2, Wfc, bfc, out);
}